// Round 6
// baseline (263.489 us; speedup 1.0000x reference)
//
#include <hip/hip_runtime.h>
#include <hip/hip_bf16.h>

// Problem constants: x [2, 2048, 768], 12 heads, head_d 64.
#define BD 2
#define SLEN 2048
#define DDIM 768
#define HNUM 12
#define HD 64
#define MROWS (BD * SLEN)   // 4096

using short4v = __attribute__((ext_vector_type(4))) short;
using short8 = __attribute__((ext_vector_type(8))) short;
using f32x4 = __attribute__((ext_vector_type(4))) float;
using uint4v = __attribute__((ext_vector_type(4))) unsigned int;

__device__ __forceinline__ short f2bf(float f) {
  __hip_bfloat16 h = __float2bfloat16(f);  // RNE
  return *reinterpret_cast<short*>(&h);
}
__device__ __forceinline__ float bf2f(short s) {
  unsigned int u = ((unsigned int)(unsigned short)s) << 16;
  float f;
  __builtin_memcpy(&f, &u, 4);
  return f;
}
__device__ __forceinline__ unsigned pkbf(float a, float b) {
  return (unsigned)(unsigned short)f2bf(a) |
         ((unsigned)(unsigned short)f2bf(b) << 16);
}

// Workspace layout (shorts):
//   [0, P)          x_hi   -- aliased as AO_hi after gemm_qkv3
//   [P, 2P)         x_lo   -- aliased as AO_lo
//   [2P, 2P+8PW)    Wq_hi, Wq_lo, Wk_hi, Wk_lo, Wv_hi, Wv_lo, Wo_hi, Wo_lo
//   [2P+8PW, +3P)   Q, K, V bf16 [B,H,S,hd]
#define P_ELEM ((size_t)MROWS * DDIM)   // 3,145,728
#define PW_ELEM ((size_t)DDIM * DDIM)   // 589,824

// ---------------------------------------------------------------------------
// Split fp32 -> bf16 (hi, lo): hi = bf16(v), lo = bf16(v - hi).
// ---------------------------------------------------------------------------
__global__ __launch_bounds__(256) void cvt_split(
    const float* __restrict__ x, const float* __restrict__ Wq,
    const float* __restrict__ Wk, const float* __restrict__ Wv,
    const float* __restrict__ Wo, short* __restrict__ ws) {
  const float* src;
  short* hi;
  size_t n;
  switch (blockIdx.z) {
    case 0:  src = x;  hi = ws;                             n = P_ELEM;  break;
    case 1:  src = Wq; hi = ws + 2 * P_ELEM;                n = PW_ELEM; break;
    case 2:  src = Wk; hi = ws + 2 * P_ELEM + 2 * PW_ELEM;  n = PW_ELEM; break;
    case 3:  src = Wv; hi = ws + 2 * P_ELEM + 4 * PW_ELEM;  n = PW_ELEM; break;
    default: src = Wo; hi = ws + 2 * P_ELEM + 6 * PW_ELEM;  n = PW_ELEM; break;
  }
  short* lo = hi + n;
  const size_t n4 = n >> 2;
  for (size_t i = (size_t)blockIdx.x * 256 + threadIdx.x; i < n4;
       i += (size_t)gridDim.x * 256) {
    float4 f = ((const float4*)src)[i];
    short4v h, l;
    h[0] = f2bf(f.x); h[1] = f2bf(f.y); h[2] = f2bf(f.z); h[3] = f2bf(f.w);
    l[0] = f2bf(f.x - bf2f(h[0]));
    l[1] = f2bf(f.y - bf2f(h[1]));
    l[2] = f2bf(f.z - bf2f(h[2]));
    l[3] = f2bf(f.w - bf2f(h[3]));
    ((short4v*)hi)[i] = h;
    ((short4v*)lo)[i] = l;
  }
}

// ---------------------------------------------------------------------------
// bf16x3 MFMA GEMM: C = A @ B^T + bias. Tile BM x BN, BK=32, 256 threads
// (4 waves, 2x2 quadrants).
// A-fragments load DIRECTLY from global (L1/L2-resident, register
// double-buffered, prefetched under MFMA) -> A never touches the LDS pipe.
// B (weights) staged in LDS [2][BN][32] linear (contiguous writes, balanced
// b128 reads) with register prefetch of the next K-step.
// Per-wave LDS ops/K-step: 8 reads + 4 writes (was 24) -> DS pipe no longer
// 5x oversubscribed vs the 48 MFMAs.
// MODE 0: fp32 out[m*768+n].  MODE 1: bf16 out scattered to [B,H,S,hd],
// value = (acc + bias) * scale.
// ---------------------------------------------------------------------------
template <int BM, int BN, int MODE>
__device__ __forceinline__ void gemm3_body(
    const short* __restrict__ Ah, const short* __restrict__ Al,
    const short* __restrict__ Bh, const short* __restrict__ Bl,
    const float* __restrict__ bias, float scale, void* __restrict__ outp) {
  __shared__ short Bs[2][BN][32];

  const int n0 = blockIdx.x * BN;
  const int m0 = blockIdx.y * BM;
  const int t = threadIdx.x;
  const int w = t >> 6, l = t & 63;
  const int wm = w >> 1, wn = w & 1;
  const int x = l & 15, g = l >> 4;

  constexpr int NI = BM / 32, NJ = BN / 32;
  constexpr int QB = BN / 64;     // 256-chunk groups per B plane
  constexpr int PERB = 2 * QB;

  f32x4 acc[NI][NJ];
  #pragma unroll
  for (int i = 0; i < NI; ++i)
    #pragma unroll
    for (int j = 0; j < NJ; ++j) acc[i][j] = (f32x4){0.f, 0.f, 0.f, 0.f};

  // Per-lane A row offsets (element units). A-frag: row = wm*(BM/2)+i*16+x,
  // k = k0 + 8g .. +8 -> lanes (x, g) cover 16 consecutive rows x 64B.
  size_t aoff[NI];
  #pragma unroll
  for (int i = 0; i < NI; ++i)
    aoff[i] = (size_t)(m0 + wm * (BM / 2) + i * 16 + x) * DDIM + 8 * g;

  short8 brg[PERB];
  auto loadB = [&](int k0) {
    #pragma unroll
    for (int q = 0; q < PERB; ++q) {
      const short* gp = (q < QB) ? Bh : Bl;
      const int local = (q % QB) * 256 + t;
      brg[q] = *(const short8*)(gp + (size_t)(n0 + (local >> 2)) * DDIM +
                                k0 + (local & 3) * 8);
    }
  };

  short8 afA[2][NI], afB[2][NI];
#define LOADA(dst, k0)                                       \
  _Pragma("unroll")                                          \
  for (int i_ = 0; i_ < NI; ++i_) {                          \
    dst[0][i_] = *(const short8*)(Ah + aoff[i_] + (k0));     \
    dst[1][i_] = *(const short8*)(Al + aoff[i_] + (k0));     \
  }

  LOADA(afA, 0);
  loadB(0);

  auto step = [&](int k0, short8 (&afU)[2][NI], short8 (&afP)[2][NI]) {
    __syncthreads();  // previous iteration's Bs readers done
    #pragma unroll
    for (int q = 0; q < PERB; ++q) {
      short* lp = (q < QB) ? &Bs[0][0][0] : &Bs[1][0][0];
      const int local = (q % QB) * 256 + t;
      *(short8*)(lp + local * 8) = brg[q];
    }
    if (k0 + 32 < DDIM) loadB(k0 + 32);  // flies during MFMA
    __syncthreads();

    short8 bf[2][NJ];
    #pragma unroll
    for (int j = 0; j < NJ; ++j) {
      bf[0][j] = *(const short8*)&Bs[0][wn * (BN / 2) + j * 16 + x][8 * g];
      bf[1][j] = *(const short8*)&Bs[1][wn * (BN / 2) + j * 16 + x][8 * g];
    }
    const int kn = (k0 + 32 < DDIM) ? (k0 + 32) : 0;  // clamped dummy at end
    LOADA(afP, kn);  // next A-frags fly during MFMA
    __builtin_amdgcn_s_setprio(1);
    #pragma unroll
    for (int i = 0; i < NI; ++i)
      #pragma unroll
      for (int j = 0; j < NJ; ++j) {
        acc[i][j] = __builtin_amdgcn_mfma_f32_16x16x32_bf16(afU[0][i], bf[0][j], acc[i][j], 0, 0, 0);
        acc[i][j] = __builtin_amdgcn_mfma_f32_16x16x32_bf16(afU[0][i], bf[1][j], acc[i][j], 0, 0, 0);
        acc[i][j] = __builtin_amdgcn_mfma_f32_16x16x32_bf16(afU[1][i], bf[0][j], acc[i][j], 0, 0, 0);
      }
    __builtin_amdgcn_s_setprio(0);
  };

  for (int kk = 0; kk < DDIM; kk += 64) {  // 12 double-steps
    step(kk, afA, afB);
    step(kk + 32, afB, afA);
  }

  // Epilogue: D col = x (n), row = 4g+reg (m).
  #pragma unroll
  for (int j = 0; j < NJ; ++j) {
    const int n = n0 + wn * (BN / 2) + j * 16 + x;
    const float bj = bias[n];
    #pragma unroll
    for (int i = 0; i < NI; ++i) {
      #pragma unroll
      for (int reg = 0; reg < 4; ++reg) {
        const int m = m0 + wm * (BM / 2) + i * 16 + 4 * g + reg;
        const float v = (acc[i][j][reg] + bj) * scale;
        if (MODE == 0) {
          ((float*)outp)[(size_t)m * DDIM + n] = v;
        } else {
          const int b_ = m >> 11, s_ = m & (SLEN - 1);
          const int h_ = n >> 6, d_ = n & (HD - 1);
          ((short*)outp)[(((size_t)(b_ * HNUM + h_) * SLEN + s_) * HD) + d_] = f2bf(v);
        }
      }
    }
  }
#undef LOADA
}

__global__ __launch_bounds__(256, 2) void gemm_qkv3(
    const short* __restrict__ ws, const float* __restrict__ bq,
    const float* __restrict__ bk, const float* __restrict__ bv,
    short* __restrict__ Qb, short* __restrict__ Kb, short* __restrict__ Vb) {
  const short* Ah = ws;
  const short* Al = ws + P_ELEM;
  const short* Bh;
  const float* bias;
  short* out;
  float scale;
  switch (blockIdx.z) {
    case 0:  Bh = ws + 2 * P_ELEM;                bias = bq; out = Qb; scale = 0.125f; break;
    case 1:  Bh = ws + 2 * P_ELEM + 2 * PW_ELEM;  bias = bk; out = Kb; scale = 1.f;   break;
    default: Bh = ws + 2 * P_ELEM + 4 * PW_ELEM;  bias = bv; out = Vb; scale = 1.f;   break;
  }
  gemm3_body<128, 128, 1>(Ah, Al, Bh, Bh + PW_ELEM, bias, scale, out);
}

__global__ __launch_bounds__(256, 2) void gemm_out3(
    const short* __restrict__ AOh, const short* __restrict__ AOl,
    const short* __restrict__ Wh, const short* __restrict__ Wl,
    const float* __restrict__ bias, float* __restrict__ out) {
  gemm3_body<64, 64, 0>(AOh, AOl, Wh, Wl, bias, 1.f, out);
}

// ---------------------------------------------------------------------------
// Flash attention fwd, causal, swapped-operand MFMA (q lane-local).
// UNCHANGED from round 5 (passed, absmax 0.0156).
// ---------------------------------------------------------------------------
__global__ __launch_bounds__(256) void flash_fwd_mfma(
    const short* __restrict__ Q, const short* __restrict__ K,
    const short* __restrict__ V, short* __restrict__ AOh,
    short* __restrict__ AOl) {
  const int bh = blockIdx.x;
  const int qt = 31 - (int)blockIdx.y;  // heavy tiles first
  const int b = bh / HNUM, h = bh % HNUM;
  const int t = threadIdx.x;
  const int w = t >> 6, l = t & 63;
  const int x = l & 15, g = l >> 4;
  const int q0 = qt * 64;
  const int qrow = q0 + 16 * w + x;

  __shared__ short Klds[128][72];   // [j][d]
  __shared__ short Vlds[64][138];   // transposed [d][j]

  short8 Qf[2];
  {
    const short* qp = Q + ((size_t)bh * SLEN + qrow) * HD;
    Qf[0] = *(const short8*)(qp + 8 * g);
    Qf[1] = *(const short8*)(qp + 8 * g + 32);
  }

  f32x4 Oacc[4];
  #pragma unroll
  for (int dc = 0; dc < 4; ++dc) Oacc[dc] = (f32x4){0.f, 0.f, 0.f, 0.f};
  float m_run = -1e30f, l_run = 0.f;

  const int ntiles = qt / 2 + 1;  // 128-wide KV tiles

  short8 krg[4], vrg[4];
  auto load_tile = [&](int kt) {
    const size_t rowb = (size_t)bh * SLEN + (size_t)kt * 128;
    #pragma unroll
    for (int q = 0; q < 4; ++q) {
      const int c = q * 256 + t;
      krg[q] = *(const short8*)(K + (rowb + (c >> 3)) * HD + (c & 7) * 8);
      vrg[q] = *(const short8*)(V + (rowb + (c >> 3)) * HD + (c & 7) * 8);
    }
  };

  load_tile(0);
  for (int kt = 0; kt < ntiles; ++kt) {
    __syncthreads();
    #pragma unroll
    for (int q = 0; q < 4; ++q) {
      const int c = q * 256 + t;
      *(short8*)&Klds[c >> 3][(c & 7) * 8] = krg[q];
      const int j = c >> 3, d0 = (c & 7) * 8;
      #pragma unroll
      for (int i = 0; i < 8; ++i) Vlds[d0 + i][j] = vrg[q][i];
    }
    if (kt + 1 < ntiles) load_tile(kt + 1);
    __syncthreads();

    f32x4 S[8];
    __builtin_amdgcn_s_setprio(1);
    #pragma unroll
    for (int jt = 0; jt < 8; ++jt) {
      short8 Kf0 = *(const short8*)&Klds[16 * jt + x][8 * g];
      short8 Kf1 = *(const short8*)&Klds[16 * jt + x][8 * g + 32];
      f32x4 z = (f32x4){0.f, 0.f, 0.f, 0.f};
      z = __builtin_amdgcn_mfma_f32_16x16x32_bf16(Kf0, Qf[0], z, 0, 0, 0);
      S[jt] = __builtin_amdgcn_mfma_f32_16x16x32_bf16(Kf1, Qf[1], z, 0, 0, 0);
    }
    __builtin_amdgcn_s_setprio(0);

    if (kt == ntiles - 1) {
      const int jb = kt * 128 + 4 * g;
      #pragma unroll
      for (int jt = 0; jt < 8; ++jt)
        #pragma unroll
        for (int r = 0; r < 4; ++r)
          if (jb + 16 * jt + r > qrow) S[jt][r] = -1e30f;
    }

    float tm = -1e30f;
    #pragma unroll
    for (int jt = 0; jt < 8; ++jt)
      #pragma unroll
      for (int r = 0; r < 4; ++r) tm = fmaxf(tm, S[jt][r]);
    tm = fmaxf(tm, __shfl_xor(tm, 16));
    tm = fmaxf(tm, __shfl_xor(tm, 32));
    const float mn = fmaxf(m_run, tm);
    const float resc = __expf(m_run - mn);
    m_run = mn;
    float ts = 0.f;
    #pragma unroll
    for (int jt = 0; jt < 8; ++jt)
      #pragma unroll
      for (int r = 0; r < 4; ++r) {
        const float p = __expf(S[jt][r] - mn);
        S[jt][r] = p;
        ts += p;
      }
    ts += __shfl_xor(ts, 16);
    ts += __shfl_xor(ts, 32);
    l_run = l_run * resc + ts;
    #pragma unroll
    for (int dc = 0; dc < 4; ++dc) Oacc[dc] *= resc;

    uint4v PA[4];
    const bool hihalf = (g >= 2);
    const bool oddg = (g & 1);
    #pragma unroll
    for (int c = 0; c < 4; ++c) {
      const unsigned e_lo = pkbf(S[2 * c][0], S[2 * c][1]);
      const unsigned e_hi = pkbf(S[2 * c][2], S[2 * c][3]);
      const unsigned o_lo = pkbf(S[2 * c + 1][0], S[2 * c + 1][1]);
      const unsigned o_hi = pkbf(S[2 * c + 1][2], S[2 * c + 1][3]);
      const unsigned xe_lo = (unsigned)__shfl_xor((int)e_lo, 32);
      const unsigned xe_hi = (unsigned)__shfl_xor((int)e_hi, 32);
      const unsigned xo_lo = (unsigned)__shfl_xor((int)o_lo, 32);
      const unsigned xo_hi = (unsigned)__shfl_xor((int)o_hi, 32);
      const unsigned ap_lo = hihalf ? xo_lo : e_lo;
      const unsigned ap_hi = hihalf ? xo_hi : e_hi;
      const unsigned bp_lo = hihalf ? o_lo : xe_lo;
      const unsigned bp_hi = hihalf ? o_hi : xe_hi;
      const unsigned sa_lo = (unsigned)__shfl_xor((int)ap_lo, 16);
      const unsigned sa_hi = (unsigned)__shfl_xor((int)ap_hi, 16);
      const unsigned sb_lo = (unsigned)__shfl_xor((int)bp_lo, 16);
      const unsigned sb_hi = (unsigned)__shfl_xor((int)bp_hi, 16);
      PA[c][0] = oddg ? sb_lo : ap_lo;
      PA[c][1] = oddg ? sb_hi : ap_hi;
      PA[c][2] = oddg ? bp_lo : sa_lo;
      PA[c][3] = oddg ? bp_hi : sa_hi;
    }

    __builtin_amdgcn_s_setprio(1);
    #pragma unroll
    for (int dc = 0; dc < 4; ++dc) {
      #pragma unroll
      for (int c = 0; c < 4; ++c) {
        short8 Vf = *(const short8*)&Vlds[16 * dc + x][32 * c + 8 * g];
        Oacc[dc] = __builtin_amdgcn_mfma_f32_16x16x32_bf16(
            Vf, *(const short8*)&PA[c], Oacc[dc], 0, 0, 0);
      }
    }
    __builtin_amdgcn_s_setprio(0);
  }

  const float inv = 1.f / l_run;
  const size_t base = ((size_t)(b * SLEN + qrow)) * DDIM + h * HD + 4 * g;
  #pragma unroll
  for (int dc = 0; dc < 4; ++dc) {
    short4v hi4, lo4;
    #pragma unroll
    for (int r = 0; r < 4; ++r) {
      const float v = Oacc[dc][r] * inv;
      const short hh = f2bf(v);
      hi4[r] = hh;
      lo4[r] = f2bf(v - bf2f(hh));
    }
    *(short4v*)(AOh + base + 16 * dc) = hi4;
    *(short4v*)(AOl + base + 16 * dc) = lo4;
  }
}

// ---------------------------------------------------------------------------
extern "C" void kernel_launch(void* const* d_in, const int* in_sizes, int n_in,
                              void* d_out, int out_size, void* d_ws, size_t ws_size,
                              hipStream_t stream) {
  const float* x  = (const float*)d_in[0];
  const float* Wq = (const float*)d_in[1];
  const float* bq = (const float*)d_in[2];
  const float* Wk = (const float*)d_in[3];
  const float* bk = (const float*)d_in[4];
  const float* Wv = (const float*)d_in[5];
  const float* bv = (const float*)d_in[6];
  const float* Wo = (const float*)d_in[7];
  const float* bo = (const float*)d_in[8];
  float* out = (float*)d_out;

  short* S = (short*)d_ws;
  short* AOh = S;                       // aliases x_hi (free after gemm_qkv3)
  short* AOl = S + P_ELEM;              // aliases x_lo
  const short* Wo_h = S + 2 * P_ELEM + 6 * PW_ELEM;
  const short* Wo_l = Wo_h + PW_ELEM;
  short* Qb = S + 2 * P_ELEM + 8 * PW_ELEM;
  short* Kb = Qb + P_ELEM;
  short* Vb = Kb + P_ELEM;

  dim3 blk(256);
  cvt_split<<<dim3(768, 1, 5), blk, 0, stream>>>(x, Wq, Wk, Wv, Wo, S);
  gemm_qkv3<<<dim3(DDIM / 128, MROWS / 128, 3), blk, 0, stream>>>(
      S, bq, bk, bv, Qb, Kb, Vb);
  flash_fwd_mfma<<<dim3(BD * HNUM, SLEN / 64), blk, 0, stream>>>(
      Qb, Kb, Vb, AOh, AOl);
  gemm_out3<<<dim3(DDIM / 64, MROWS / 64), blk, 0, stream>>>(
      AOh, AOl, Wo_h, Wo_l, bo, out);
}

// Round 8
// 222.401 us; speedup vs baseline: 1.1847x; 1.1847x over previous
//
#include <hip/hip_runtime.h>
#include <hip/hip_bf16.h>

// Problem constants: x [2, 2048, 768], 12 heads, head_d 64.
#define BD 2
#define SLEN 2048
#define DDIM 768
#define HNUM 12
#define HD 64
#define MROWS (BD * SLEN)   // 4096

using short4v = __attribute__((ext_vector_type(4))) short;
using short8 = __attribute__((ext_vector_type(8))) short;
using f32x4 = __attribute__((ext_vector_type(4))) float;
using uint4v = __attribute__((ext_vector_type(4))) unsigned int;

__device__ __forceinline__ short f2bf(float f) {
  __hip_bfloat16 h = __float2bfloat16(f);  // RNE
  return *reinterpret_cast<short*>(&h);
}
__device__ __forceinline__ float bf2f(short s) {
  unsigned int u = ((unsigned int)(unsigned short)s) << 16;
  float f;
  __builtin_memcpy(&f, &u, 4);
  return f;
}
__device__ __forceinline__ unsigned pkbf(float a, float b) {
  return (unsigned)(unsigned short)f2bf(a) |
         ((unsigned)(unsigned short)f2bf(b) << 16);
}
// Async global->LDS DMA, 16 B per lane. LDS dest is wave-uniform base +
// lane*16 (m104); global src is per-lane.
__device__ __forceinline__ void gload16(const short* g, short* l) {
  __builtin_amdgcn_global_load_lds(
      (const __attribute__((address_space(1))) unsigned int*)g,
      (__attribute__((address_space(3))) unsigned int*)l, 16, 0, 0);
}

// Workspace layout (shorts):
//   [0, P)          x_hi   -- aliased as AO_hi after gemm_qkv3
//   [P, 2P)         x_lo   -- aliased as AO_lo
//   [2P, 2P+8PW)    Wq_hi, Wq_lo, Wk_hi, Wk_lo, Wv_hi, Wv_lo, Wo_hi, Wo_lo
//   [2P+8PW, +3P)   Q, K, V bf16 [B,H,S,hd]
#define P_ELEM ((size_t)MROWS * DDIM)   // 3,145,728
#define PW_ELEM ((size_t)DDIM * DDIM)   // 589,824

// ---------------------------------------------------------------------------
// Split fp32 -> bf16 (hi, lo): hi = bf16(v), lo = bf16(v - hi).
// ---------------------------------------------------------------------------
__global__ __launch_bounds__(256) void cvt_split(
    const float* __restrict__ x, const float* __restrict__ Wq,
    const float* __restrict__ Wk, const float* __restrict__ Wv,
    const float* __restrict__ Wo, short* __restrict__ ws) {
  const float* src;
  short* hi;
  size_t n;
  switch (blockIdx.z) {
    case 0:  src = x;  hi = ws;                             n = P_ELEM;  break;
    case 1:  src = Wq; hi = ws + 2 * P_ELEM;                n = PW_ELEM; break;
    case 2:  src = Wk; hi = ws + 2 * P_ELEM + 2 * PW_ELEM;  n = PW_ELEM; break;
    case 3:  src = Wv; hi = ws + 2 * P_ELEM + 4 * PW_ELEM;  n = PW_ELEM; break;
    default: src = Wo; hi = ws + 2 * P_ELEM + 6 * PW_ELEM;  n = PW_ELEM; break;
  }
  short* lo = hi + n;
  const size_t n4 = n >> 2;
  for (size_t i = (size_t)blockIdx.x * 256 + threadIdx.x; i < n4;
       i += (size_t)gridDim.x * 256) {
    float4 f = ((const float4*)src)[i];
    short4v h, l;
    h[0] = f2bf(f.x); h[1] = f2bf(f.y); h[2] = f2bf(f.z); h[3] = f2bf(f.w);
    l[0] = f2bf(f.x - bf2f(h[0]));
    l[1] = f2bf(f.y - bf2f(h[1]));
    l[2] = f2bf(f.z - bf2f(h[2]));
    l[3] = f2bf(f.w - bf2f(h[3]));
    ((short4v*)hi)[i] = h;
    ((short4v*)lo)[i] = l;
  }
}

// ---------------------------------------------------------------------------
// bf16x3 MFMA GEMM: C = A @ B^T + bias. Tile BM x BN, BK=32, 256 threads
// (4 waves, 2x2 quadrants), double-buffered LDS.
// Staging: global_load_lds width=16 for all 4 planes (linear LDS dest =
// exactly the chunk map local = q*256+t, 16 B/chunk). No ds_writes, no
// register round-trip. DS issue path = 16 frag ds_read_b128/wave/K-step.
// Frag-read bank fix: k-chunk XOR-swizzled by row (ks = g ^ ((row>>1)&3)),
// applied to BOTH the pre-swizzled global source and the read (rule #21)
// -> 8-way conflict becomes 2-way (free).
// MODE 0: fp32 out[m*768+n].  MODE 1: bf16 out scattered to [B,H,S,hd],
// value = (acc + bias) * scale.
// ---------------------------------------------------------------------------
template <int BM, int BN, int MODE>
__device__ __forceinline__ void gemm3_body(
    const short* __restrict__ Ah, const short* __restrict__ Al,
    const short* __restrict__ Bh, const short* __restrict__ Bl,
    const float* __restrict__ bias, float scale, void* __restrict__ outp) {
  __shared__ short As[2][2][BM][32];  // [buf][hi/lo][row][k]
  __shared__ short Bs[2][2][BN][32];

  const int n0 = blockIdx.x * BN;
  const int m0 = blockIdx.y * BM;
  const int t = threadIdx.x;
  const int w = t >> 6, l = t & 63;
  const int wm = w >> 1, wn = w & 1;
  const int x = l & 15, g = l >> 4;

  constexpr int NI = BM / 32, NJ = BN / 32;
  constexpr int QA = BM / 64;   // 256-chunk groups per plane
  constexpr int QB = BN / 64;

  f32x4 acc[NI][NJ];
  #pragma unroll
  for (int i = 0; i < NI; ++i)
    #pragma unroll
    for (int j = 0; j < NJ; ++j) acc[i][j] = (f32x4){0.f, 0.f, 0.f, 0.f};

  // Issue DMA for K-step k0 into buffer bb. Chunk local = q*256+t:
  // row = local>>2, k-slot source = (local&3) ^ ((row>>1)&3)  (pre-swizzle).
  // Wave-uniform LDS base chunk = q*256 + (t & 192); lane adds l*16 B.
  auto stage = [&](int bb, int k0) {
    #pragma unroll
    for (int q = 0; q < QA; ++q) {
      const int local = q * 256 + t;
      const int row = local >> 2;
      const int ks = (local & 3) ^ ((row >> 1) & 3);
      const int lbase = (q * 256 + (t & 192)) * 8;  // shorts
      const size_t go = (size_t)(m0 + row) * DDIM + k0 + ks * 8;
      gload16(Ah + go, &As[bb][0][0][0] + lbase);
      gload16(Al + go, &As[bb][1][0][0] + lbase);
    }
    #pragma unroll
    for (int q = 0; q < QB; ++q) {
      const int local = q * 256 + t;
      const int row = local >> 2;
      const int ks = (local & 3) ^ ((row >> 1) & 3);
      const int lbase = (q * 256 + (t & 192)) * 8;
      const size_t go = (size_t)(n0 + row) * DDIM + k0 + ks * 8;
      gload16(Bh + go, &Bs[bb][0][0][0] + lbase);
      gload16(Bl + go, &Bs[bb][1][0][0] + lbase);
    }
  };

  stage(0, 0);
  int cur = 0;
  for (int k0 = 0; k0 < DDIM; k0 += 32) {
    __syncthreads();  // drains cur-buf DMA (vmcnt0) + prev readers of cur^1
    if (k0 + 32 < DDIM) stage(cur ^ 1, k0 + 32);  // flies during compute

    short8 af[2][NI], bf[2][NJ];
    #pragma unroll
    for (int i = 0; i < NI; ++i) {
      const int row = wm * (BM / 2) + i * 16 + x;
      const int ks = g ^ ((row >> 1) & 3);
      af[0][i] = *(const short8*)&As[cur][0][row][ks * 8];
      af[1][i] = *(const short8*)&As[cur][1][row][ks * 8];
    }
    #pragma unroll
    for (int j = 0; j < NJ; ++j) {
      const int row = wn * (BN / 2) + j * 16 + x;
      const int ks = g ^ ((row >> 1) & 3);
      bf[0][j] = *(const short8*)&Bs[cur][0][row][ks * 8];
      bf[1][j] = *(const short8*)&Bs[cur][1][row][ks * 8];
    }
    __builtin_amdgcn_s_setprio(1);
    #pragma unroll
    for (int i = 0; i < NI; ++i)
      #pragma unroll
      for (int j = 0; j < NJ; ++j) {
        acc[i][j] = __builtin_amdgcn_mfma_f32_16x16x32_bf16(af[0][i], bf[0][j], acc[i][j], 0, 0, 0);
        acc[i][j] = __builtin_amdgcn_mfma_f32_16x16x32_bf16(af[0][i], bf[1][j], acc[i][j], 0, 0, 0);
        acc[i][j] = __builtin_amdgcn_mfma_f32_16x16x32_bf16(af[1][i], bf[0][j], acc[i][j], 0, 0, 0);
      }
    __builtin_amdgcn_s_setprio(0);
    cur ^= 1;
  }

  // Epilogue: D col = x (n), row = 4g+reg (m).
  #pragma unroll
  for (int j = 0; j < NJ; ++j) {
    const int n = n0 + wn * (BN / 2) + j * 16 + x;
    const float bj = bias[n];
    #pragma unroll
    for (int i = 0; i < NI; ++i) {
      #pragma unroll
      for (int reg = 0; reg < 4; ++reg) {
        const int m = m0 + wm * (BM / 2) + i * 16 + 4 * g + reg;
        const float v = (acc[i][j][reg] + bj) * scale;
        if (MODE == 0) {
          ((float*)outp)[(size_t)m * DDIM + n] = v;
        } else {
          const int b_ = m >> 11, s_ = m & (SLEN - 1);
          const int h_ = n >> 6, d_ = n & (HD - 1);
          ((short*)outp)[(((size_t)(b_ * HNUM + h_) * SLEN + s_) * HD) + d_] = f2bf(v);
        }
      }
    }
  }
}

__global__ __launch_bounds__(256, 2) void gemm_qkv3(
    const short* __restrict__ ws, const float* __restrict__ bq,
    const float* __restrict__ bk, const float* __restrict__ bv,
    short* __restrict__ Qb, short* __restrict__ Kb, short* __restrict__ Vb) {
  const short* Ah = ws;
  const short* Al = ws + P_ELEM;
  const short* Bh;
  const float* bias;
  short* out;
  float scale;
  switch (blockIdx.z) {
    case 0:  Bh = ws + 2 * P_ELEM;                bias = bq; out = Qb; scale = 0.125f; break;
    case 1:  Bh = ws + 2 * P_ELEM + 2 * PW_ELEM;  bias = bk; out = Kb; scale = 1.f;   break;
    default: Bh = ws + 2 * P_ELEM + 4 * PW_ELEM;  bias = bv; out = Vb; scale = 1.f;   break;
  }
  gemm3_body<128, 128, 1>(Ah, Al, Bh, Bh + PW_ELEM, bias, scale, out);
}

__global__ __launch_bounds__(256, 2) void gemm_out3(
    const short* __restrict__ AOh, const short* __restrict__ AOl,
    const short* __restrict__ Wh, const short* __restrict__ Wl,
    const float* __restrict__ bias, float* __restrict__ out) {
  gemm3_body<64, 64, 0>(AOh, AOl, Wh, Wl, bias, 1.f, out);
}

// ---------------------------------------------------------------------------
// Flash attention fwd, causal, swapped-operand MFMA (q lane-local).
// UNCHANGED from round 5 (passed, absmax 0.0156, <67 us).
// ---------------------------------------------------------------------------
__global__ __launch_bounds__(256) void flash_fwd_mfma(
    const short* __restrict__ Q, const short* __restrict__ K,
    const short* __restrict__ V, short* __restrict__ AOh,
    short* __restrict__ AOl) {
  const int bh = blockIdx.x;
  const int qt = 31 - (int)blockIdx.y;  // heavy tiles first
  const int b = bh / HNUM, h = bh % HNUM;
  const int t = threadIdx.x;
  const int w = t >> 6, l = t & 63;
  const int x = l & 15, g = l >> 4;
  const int q0 = qt * 64;
  const int qrow = q0 + 16 * w + x;

  __shared__ short Klds[128][72];   // [j][d]
  __shared__ short Vlds[64][138];   // transposed [d][j]

  short8 Qf[2];
  {
    const short* qp = Q + ((size_t)bh * SLEN + qrow) * HD;
    Qf[0] = *(const short8*)(qp + 8 * g);
    Qf[1] = *(const short8*)(qp + 8 * g + 32);
  }

  f32x4 Oacc[4];
  #pragma unroll
  for (int dc = 0; dc < 4; ++dc) Oacc[dc] = (f32x4){0.f, 0.f, 0.f, 0.f};
  float m_run = -1e30f, l_run = 0.f;

  const int ntiles = qt / 2 + 1;  // 128-wide KV tiles

  short8 krg[4], vrg[4];
  auto load_tile = [&](int kt) {
    const size_t rowb = (size_t)bh * SLEN + (size_t)kt * 128;
    #pragma unroll
    for (int q = 0; q < 4; ++q) {
      const int c = q * 256 + t;
      krg[q] = *(const short8*)(K + (rowb + (c >> 3)) * HD + (c & 7) * 8);
      vrg[q] = *(const short8*)(V + (rowb + (c >> 3)) * HD + (c & 7) * 8);
    }
  };

  load_tile(0);
  for (int kt = 0; kt < ntiles; ++kt) {
    __syncthreads();
    #pragma unroll
    for (int q = 0; q < 4; ++q) {
      const int c = q * 256 + t;
      *(short8*)&Klds[c >> 3][(c & 7) * 8] = krg[q];
      const int j = c >> 3, d0 = (c & 7) * 8;
      #pragma unroll
      for (int i = 0; i < 8; ++i) Vlds[d0 + i][j] = vrg[q][i];
    }
    if (kt + 1 < ntiles) load_tile(kt + 1);
    __syncthreads();

    f32x4 S[8];
    __builtin_amdgcn_s_setprio(1);
    #pragma unroll
    for (int jt = 0; jt < 8; ++jt) {
      short8 Kf0 = *(const short8*)&Klds[16 * jt + x][8 * g];
      short8 Kf1 = *(const short8*)&Klds[16 * jt + x][8 * g + 32];
      f32x4 z = (f32x4){0.f, 0.f, 0.f, 0.f};
      z = __builtin_amdgcn_mfma_f32_16x16x32_bf16(Kf0, Qf[0], z, 0, 0, 0);
      S[jt] = __builtin_amdgcn_mfma_f32_16x16x32_bf16(Kf1, Qf[1], z, 0, 0, 0);
    }
    __builtin_amdgcn_s_setprio(0);

    if (kt == ntiles - 1) {
      const int jb = kt * 128 + 4 * g;
      #pragma unroll
      for (int jt = 0; jt < 8; ++jt)
        #pragma unroll
        for (int r = 0; r < 4; ++r)
          if (jb + 16 * jt + r > qrow) S[jt][r] = -1e30f;
    }

    float tm = -1e30f;
    #pragma unroll
    for (int jt = 0; jt < 8; ++jt)
      #pragma unroll
      for (int r = 0; r < 4; ++r) tm = fmaxf(tm, S[jt][r]);
    tm = fmaxf(tm, __shfl_xor(tm, 16));
    tm = fmaxf(tm, __shfl_xor(tm, 32));
    const float mn = fmaxf(m_run, tm);
    const float resc = __expf(m_run - mn);
    m_run = mn;
    float ts = 0.f;
    #pragma unroll
    for (int jt = 0; jt < 8; ++jt)
      #pragma unroll
      for (int r = 0; r < 4; ++r) {
        const float p = __expf(S[jt][r] - mn);
        S[jt][r] = p;
        ts += p;
      }
    ts += __shfl_xor(ts, 16);
    ts += __shfl_xor(ts, 32);
    l_run = l_run * resc + ts;
    #pragma unroll
    for (int dc = 0; dc < 4; ++dc) Oacc[dc] *= resc;

    uint4v PA[4];
    const bool hihalf = (g >= 2);
    const bool oddg = (g & 1);
    #pragma unroll
    for (int c = 0; c < 4; ++c) {
      const unsigned e_lo = pkbf(S[2 * c][0], S[2 * c][1]);
      const unsigned e_hi = pkbf(S[2 * c][2], S[2 * c][3]);
      const unsigned o_lo = pkbf(S[2 * c + 1][0], S[2 * c + 1][1]);
      const unsigned o_hi = pkbf(S[2 * c + 1][2], S[2 * c + 1][3]);
      const unsigned xe_lo = (unsigned)__shfl_xor((int)e_lo, 32);
      const unsigned xe_hi = (unsigned)__shfl_xor((int)e_hi, 32);
      const unsigned xo_lo = (unsigned)__shfl_xor((int)o_lo, 32);
      const unsigned xo_hi = (unsigned)__shfl_xor((int)o_hi, 32);
      const unsigned ap_lo = hihalf ? xo_lo : e_lo;
      const unsigned ap_hi = hihalf ? xo_hi : e_hi;
      const unsigned bp_lo = hihalf ? o_lo : xe_lo;
      const unsigned bp_hi = hihalf ? o_hi : xe_hi;
      const unsigned sa_lo = (unsigned)__shfl_xor((int)ap_lo, 16);
      const unsigned sa_hi = (unsigned)__shfl_xor((int)ap_hi, 16);
      const unsigned sb_lo = (unsigned)__shfl_xor((int)bp_lo, 16);
      const unsigned sb_hi = (unsigned)__shfl_xor((int)bp_hi, 16);
      PA[c][0] = oddg ? sb_lo : ap_lo;
      PA[c][1] = oddg ? sb_hi : ap_hi;
      PA[c][2] = oddg ? bp_lo : sa_lo;
      PA[c][3] = oddg ? bp_hi : sa_hi;
    }

    __builtin_amdgcn_s_setprio(1);
    #pragma unroll
    for (int dc = 0; dc < 4; ++dc) {
      #pragma unroll
      for (int c = 0; c < 4; ++c) {
        short8 Vf = *(const short8*)&Vlds[16 * dc + x][32 * c + 8 * g];
        Oacc[dc] = __builtin_amdgcn_mfma_f32_16x16x32_bf16(
            Vf, *(const short8*)&PA[c], Oacc[dc], 0, 0, 0);
      }
    }
    __builtin_amdgcn_s_setprio(0);
  }

  const float inv = 1.f / l_run;
  const size_t base = ((size_t)(b * SLEN + qrow)) * DDIM + h * HD + 4 * g;
  #pragma unroll
  for (int dc = 0; dc < 4; ++dc) {
    short4v hi4, lo4;
    #pragma unroll
    for (int r = 0; r < 4; ++r) {
      const float v = Oacc[dc][r] * inv;
      const short hh = f2bf(v);
      hi4[r] = hh;
      lo4[r] = f2bf(v - bf2f(hh));
    }
    *(short4v*)(AOh + base + 16 * dc) = hi4;
    *(short4v*)(AOl + base + 16 * dc) = lo4;
  }
}

// ---------------------------------------------------------------------------
extern "C" void kernel_launch(void* const* d_in, const int* in_sizes, int n_in,
                              void* d_out, int out_size, void* d_ws, size_t ws_size,
                              hipStream_t stream) {
  const float* x  = (const float*)d_in[0];
  const float* Wq = (const float*)d_in[1];
  const float* bq = (const float*)d_in[2];
  const float* Wk = (const float*)d_in[3];
  const float* bk = (const float*)d_in[4];
  const float* Wv = (const float*)d_in[5];
  const float* bv = (const float*)d_in[6];
  const float* Wo = (const float*)d_in[7];
  const float* bo = (const float*)d_in[8];
  float* out = (float*)d_out;

  short* S = (short*)d_ws;
  short* AOh = S;                       // aliases x_hi (free after gemm_qkv3)
  short* AOl = S + P_ELEM;              // aliases x_lo
  const short* Wo_h = S + 2 * P_ELEM + 6 * PW_ELEM;
  const short* Wo_l = Wo_h + PW_ELEM;
  short* Qb = S + 2 * P_ELEM + 8 * PW_ELEM;
  short* Kb = Qb + P_ELEM;
  short* Vb = Kb + P_ELEM;

  dim3 blk(256);
  cvt_split<<<dim3(768, 1, 5), blk, 0, stream>>>(x, Wq, Wk, Wv, Wo, S);
  gemm_qkv3<<<dim3(DDIM / 128, MROWS / 128, 3), blk, 0, stream>>>(
      S, bq, bk, bv, Qb, Kb, Vb);
  flash_fwd_mfma<<<dim3(BD * HNUM, SLEN / 64), blk, 0, stream>>>(
      Qb, Kb, Vb, AOh, AOl);
  gemm_out3<<<dim3(DDIM / 64, MROWS / 64), blk, 0, stream>>>(
      AOh, AOl, Wo_h, Wo_l, bo, out);
}

// Round 9
// 205.664 us; speedup vs baseline: 1.2812x; 1.0814x over previous
//
#include <hip/hip_runtime.h>
#include <hip/hip_bf16.h>

// Problem constants: x [2, 2048, 768], 12 heads, head_d 64.
#define BD 2
#define SLEN 2048
#define DDIM 768
#define HNUM 12
#define HD 64
#define MROWS (BD * SLEN)   // 4096
#define KC_N (DDIM / 32)    // 24 k-chunks

using short4v = __attribute__((ext_vector_type(4))) short;
using short8 = __attribute__((ext_vector_type(8))) short;
using f32x4 = __attribute__((ext_vector_type(4))) float;
using uint4v = __attribute__((ext_vector_type(4))) unsigned int;

__device__ __forceinline__ short f2bf(float f) {
  __hip_bfloat16 h = __float2bfloat16(f);  // RNE
  return *reinterpret_cast<short*>(&h);
}
__device__ __forceinline__ float bf2f(short s) {
  unsigned int u = ((unsigned int)(unsigned short)s) << 16;
  float f;
  __builtin_memcpy(&f, &u, 4);
  return f;
}
__device__ __forceinline__ unsigned pkbf(float a, float b) {
  return (unsigned)(unsigned short)f2bf(a) |
         ((unsigned)(unsigned short)f2bf(b) << 16);
}
// Async global->LDS DMA, 16 B per lane. LDS dest is wave-uniform base +
// lane*16 (m104); global src is per-lane.
__device__ __forceinline__ void gload16(const short* g, short* l) {
  __builtin_amdgcn_global_load_lds(
      (const __attribute__((address_space(1))) unsigned int*)g,
      (__attribute__((address_space(3))) unsigned int*)l, 16, 0, 0);
}

// Fragment layout for lo planes: [row/16][k/32][lane=g*16+x][8 shorts]
// element (m = tile*16 + x, k = kc*32 + g*8 + e). One frag = 1 KB.
// A lo-fragment load is global_load_dwordx4 at uniform base + lane*16.
__device__ __forceinline__ size_t frag_off(int tile, int kc, int lane8) {
  return ((size_t)tile * KC_N + kc) * 512 + lane8;
}

// Workspace layout (shorts):
//   [0, P)          x_hi (row-major)        -- aliased AO_hi after qkv3
//   [P, 2P)         x_lo (FRAG layout)      -- aliased AO_lo (frag)
//   [2P, 2P+8PW)    Wq_hi, Wq_lo(frag), Wk_hi, Wk_lo(frag), Wv..., Wo...
//   [2P+8PW, +3P)   Q, K, V bf16 [B,H,S,hd]
#define P_ELEM ((size_t)MROWS * DDIM)   // 3,145,728
#define PW_ELEM ((size_t)DDIM * DDIM)   // 589,824

// ---------------------------------------------------------------------------
// Split fp32 -> bf16 hi (row-major) + lo (fragment layout).
// ---------------------------------------------------------------------------
__global__ __launch_bounds__(256) void cvt_split(
    const float* __restrict__ x, const float* __restrict__ Wq,
    const float* __restrict__ Wk, const float* __restrict__ Wv,
    const float* __restrict__ Wo, short* __restrict__ ws) {
  const float* src;
  short* hi;
  size_t n;
  switch (blockIdx.z) {
    case 0:  src = x;  hi = ws;                             n = P_ELEM;  break;
    case 1:  src = Wq; hi = ws + 2 * P_ELEM;                n = PW_ELEM; break;
    case 2:  src = Wk; hi = ws + 2 * P_ELEM + 2 * PW_ELEM;  n = PW_ELEM; break;
    case 3:  src = Wv; hi = ws + 2 * P_ELEM + 4 * PW_ELEM;  n = PW_ELEM; break;
    default: src = Wo; hi = ws + 2 * P_ELEM + 6 * PW_ELEM;  n = PW_ELEM; break;
  }
  short* lo = hi + n;
  const size_t n4 = n >> 2;
  for (size_t i = (size_t)blockIdx.x * 256 + threadIdx.x; i < n4;
       i += (size_t)gridDim.x * 256) {
    float4 f = ((const float4*)src)[i];
    short4v h, l;
    h[0] = f2bf(f.x); h[1] = f2bf(f.y); h[2] = f2bf(f.z); h[3] = f2bf(f.w);
    l[0] = f2bf(f.x - bf2f(h[0]));
    l[1] = f2bf(f.y - bf2f(h[1]));
    l[2] = f2bf(f.z - bf2f(h[2]));
    l[3] = f2bf(f.w - bf2f(h[3]));
    ((short4v*)hi)[i] = h;
    // lo -> frag layout. 4 floats at (row, k..k+3), k % 4 == 0.
    const int f0 = (int)(i << 2);
    const int row = f0 / DDIM, k = f0 % DDIM;
    const size_t lof = frag_off(row >> 4, k >> 5,
                                ((((k >> 3) & 3) << 4) + (row & 15)) * 8) +
                       (k & 7);
    *(short4v*)(lo + lof) = l;
  }
}

// ---------------------------------------------------------------------------
// bf16x3 MFMA GEMM: C = A @ B^T + bias. Tile BM x BN, BK=32, 256 threads
// (4 waves, 2x2 quadrants), double-buffered hi-only LDS.
//   hi planes: global_load_lds DMA (pre-swizzled source, swizzled read:
//              ks = g ^ ((row>>1)&3), linear dest — rule #21, 0 conflicts/r8)
//   lo planes: fragment-layout global loads (coalesced 1KB, L2-resident),
//              issued before the barrier so latency drains with vmcnt(0).
// LDS = (BM+BN)*32*2B*2buf -> 3 blocks/CU; grids sized to exactly 3*256
// blocks (qkv3: BN=96 -> 8*32*3 = 768; out3: 64x64 -> 12*64 = 768) — no
// wave-quantization tail (r8's 576-on-512 cost ~40%).
// MODE 0: fp32 out[m*768+n].  MODE 1: bf16 out scattered to [B,H,S,hd].
// ---------------------------------------------------------------------------
template <int BM, int BN, int MODE>
__device__ __forceinline__ void gemm3_body(
    const short* __restrict__ Ah, const short* __restrict__ Alo,
    const short* __restrict__ Bh, const short* __restrict__ Blo,
    const float* __restrict__ bias, float scale, void* __restrict__ outp) {
  __shared__ short As[2][BM][32];  // hi only
  __shared__ short Bs[2][BN][32];

  const int n0 = blockIdx.x * BN;
  const int m0 = blockIdx.y * BM;
  const int t = threadIdx.x;
  const int w = t >> 6, l = t & 63;
  const int wm = w >> 1, wn = w & 1;
  const int x = l & 15, g = l >> 4;

  constexpr int NI = BM / 64;        // 16-row positions per wave (M)
  constexpr int NJ = BN / 32;        // 16-col positions per wave (N)
  constexpr int ACH = BM * 4;        // 16B chunks per A plane
  constexpr int BCH = BN * 4;

  f32x4 acc[NI * 2][NJ];
  #pragma unroll
  for (int i = 0; i < NI * 2; ++i)
    #pragma unroll
    for (int j = 0; j < NJ; ++j) acc[i][j] = (f32x4){0.f, 0.f, 0.f, 0.f};

  auto stage = [&](int bb, int k0) {
    #pragma unroll
    for (int q = 0; q < (ACH + 255) / 256; ++q) {
      const int c = q * 256 + t;
      if (ACH % 256 == 0 || c < ACH) {
        const int row = c >> 2;
        const int ks = (c & 3) ^ ((row >> 1) & 3);
        gload16(Ah + (size_t)(m0 + row) * DDIM + k0 + ks * 8,
                &As[bb][0][0] + (q * 256 + (t & 192)) * 8);
      }
    }
    #pragma unroll
    for (int q = 0; q < (BCH + 255) / 256; ++q) {
      const int c = q * 256 + t;
      if (BCH % 256 == 0 || c < BCH) {
        const int row = c >> 2;
        const int ks = (c & 3) ^ ((row >> 1) & 3);
        gload16(Bh + (size_t)(n0 + row) * DDIM + k0 + ks * 8,
                &Bs[bb][0][0] + (q * 256 + (t & 192)) * 8);
      }
    }
  };

  const int l8 = l * 8;
  stage(0, 0);
  int cur = 0;
  for (int k0 = 0; k0 < DDIM; k0 += 32) {
    const int kc = k0 >> 5;
    // lo fragments (global, frag layout) — issue BEFORE the barrier so the
    // barrier's vmcnt(0) drain covers their latency.
    short8 alo[NI * 2], blo[NJ];
    #pragma unroll
    for (int i = 0; i < NI * 2; ++i) {
      const int mt = (m0 >> 4) + wm * (BM / 32) + i;
      alo[i] = *(const short8*)(Alo + frag_off(mt, kc, l8));
    }
    #pragma unroll
    for (int j = 0; j < NJ; ++j) {
      const int nt = (n0 >> 4) + wn * (BN / 32) + j;
      blo[j] = *(const short8*)(Blo + frag_off(nt, kc, l8));
    }
    __syncthreads();  // drains cur-buf DMA + lo loads; prev readers done
    if (k0 + 32 < DDIM) stage(cur ^ 1, k0 + 32);  // flies during compute

    short8 afh[NI * 2], bfh[NJ];
    #pragma unroll
    for (int i = 0; i < NI * 2; ++i) {
      const int row = wm * (BM / 2) + i * 16 + x;
      const int ks = g ^ ((row >> 1) & 3);
      afh[i] = *(const short8*)&As[cur][row][ks * 8];
    }
    #pragma unroll
    for (int j = 0; j < NJ; ++j) {
      const int row = wn * (BN / 2) + j * 16 + x;
      const int ks = g ^ ((row >> 1) & 3);
      bfh[j] = *(const short8*)&Bs[cur][row][ks * 8];
    }
    __builtin_amdgcn_s_setprio(1);
    #pragma unroll
    for (int i = 0; i < NI * 2; ++i)
      #pragma unroll
      for (int j = 0; j < NJ; ++j) {
        acc[i][j] = __builtin_amdgcn_mfma_f32_16x16x32_bf16(afh[i], bfh[j], acc[i][j], 0, 0, 0);
        acc[i][j] = __builtin_amdgcn_mfma_f32_16x16x32_bf16(afh[i], blo[j], acc[i][j], 0, 0, 0);
        acc[i][j] = __builtin_amdgcn_mfma_f32_16x16x32_bf16(alo[i], bfh[j], acc[i][j], 0, 0, 0);
      }
    __builtin_amdgcn_s_setprio(0);
    cur ^= 1;
  }

  // Epilogue: D col = x (n), row = 4g+reg (m).
  #pragma unroll
  for (int j = 0; j < NJ; ++j) {
    const int n = n0 + wn * (BN / 2) + j * 16 + x;
    const float bj = bias[n];
    #pragma unroll
    for (int i = 0; i < NI * 2; ++i) {
      #pragma unroll
      for (int reg = 0; reg < 4; ++reg) {
        const int m = m0 + wm * (BM / 2) + i * 16 + 4 * g + reg;
        const float v = (acc[i][j][reg] + bj) * scale;
        if (MODE == 0) {
          ((float*)outp)[(size_t)m * DDIM + n] = v;
        } else {
          const int b_ = m >> 11, s_ = m & (SLEN - 1);
          const int h_ = n >> 6, d_ = n & (HD - 1);
          ((short*)outp)[(((size_t)(b_ * HNUM + h_) * SLEN + s_) * HD) + d_] = f2bf(v);
        }
      }
    }
  }
}

__global__ __launch_bounds__(256, 3) void gemm_qkv3(
    const short* __restrict__ ws, const float* __restrict__ bq,
    const float* __restrict__ bk, const float* __restrict__ bv,
    short* __restrict__ Qb, short* __restrict__ Kb, short* __restrict__ Vb) {
  const short* Ah = ws;
  const short* Alo = ws + P_ELEM;
  const short* Bh;
  const float* bias;
  short* out;
  float scale;
  switch (blockIdx.z) {
    case 0:  Bh = ws + 2 * P_ELEM;                bias = bq; out = Qb; scale = 0.125f; break;
    case 1:  Bh = ws + 2 * P_ELEM + 2 * PW_ELEM;  bias = bk; out = Kb; scale = 1.f;   break;
    default: Bh = ws + 2 * P_ELEM + 4 * PW_ELEM;  bias = bv; out = Vb; scale = 1.f;   break;
  }
  gemm3_body<128, 96, 1>(Ah, Alo, Bh, Bh + PW_ELEM, bias, scale, out);
}

__global__ __launch_bounds__(256, 3) void gemm_out3(
    const short* __restrict__ AOh, const short* __restrict__ AOl,
    const short* __restrict__ Wh, const short* __restrict__ Wl,
    const float* __restrict__ bias, float* __restrict__ out) {
  gemm3_body<64, 64, 0>(AOh, AOl, Wh, Wl, bias, 1.f, out);
}

// ---------------------------------------------------------------------------
// Flash attention fwd, causal, swapped-operand MFMA (q lane-local).
// Identical to r5/r8 except the AO_lo epilogue writes FRAG layout.
// ---------------------------------------------------------------------------
__global__ __launch_bounds__(256) void flash_fwd_mfma(
    const short* __restrict__ Q, const short* __restrict__ K,
    const short* __restrict__ V, short* __restrict__ AOh,
    short* __restrict__ AOl) {
  const int bh = blockIdx.x;
  const int qt = 31 - (int)blockIdx.y;  // heavy tiles first
  const int b = bh / HNUM, h = bh % HNUM;
  const int t = threadIdx.x;
  const int w = t >> 6, l = t & 63;
  const int x = l & 15, g = l >> 4;
  const int q0 = qt * 64;
  const int qrow = q0 + 16 * w + x;

  __shared__ short Klds[128][72];   // [j][d]
  __shared__ short Vlds[64][138];   // transposed [d][j]

  short8 Qf[2];
  {
    const short* qp = Q + ((size_t)bh * SLEN + qrow) * HD;
    Qf[0] = *(const short8*)(qp + 8 * g);
    Qf[1] = *(const short8*)(qp + 8 * g + 32);
  }

  f32x4 Oacc[4];
  #pragma unroll
  for (int dc = 0; dc < 4; ++dc) Oacc[dc] = (f32x4){0.f, 0.f, 0.f, 0.f};
  float m_run = -1e30f, l_run = 0.f;

  const int ntiles = qt / 2 + 1;  // 128-wide KV tiles

  short8 krg[4], vrg[4];
  auto load_tile = [&](int kt) {
    const size_t rowb = (size_t)bh * SLEN + (size_t)kt * 128;
    #pragma unroll
    for (int q = 0; q < 4; ++q) {
      const int c = q * 256 + t;
      krg[q] = *(const short8*)(K + (rowb + (c >> 3)) * HD + (c & 7) * 8);
      vrg[q] = *(const short8*)(V + (rowb + (c >> 3)) * HD + (c & 7) * 8);
    }
  };

  load_tile(0);
  for (int kt = 0; kt < ntiles; ++kt) {
    __syncthreads();
    #pragma unroll
    for (int q = 0; q < 4; ++q) {
      const int c = q * 256 + t;
      *(short8*)&Klds[c >> 3][(c & 7) * 8] = krg[q];
      const int j = c >> 3, d0 = (c & 7) * 8;
      #pragma unroll
      for (int i = 0; i < 8; ++i) Vlds[d0 + i][j] = vrg[q][i];
    }
    if (kt + 1 < ntiles) load_tile(kt + 1);
    __syncthreads();

    f32x4 S[8];
    __builtin_amdgcn_s_setprio(1);
    #pragma unroll
    for (int jt = 0; jt < 8; ++jt) {
      short8 Kf0 = *(const short8*)&Klds[16 * jt + x][8 * g];
      short8 Kf1 = *(const short8*)&Klds[16 * jt + x][8 * g + 32];
      f32x4 z = (f32x4){0.f, 0.f, 0.f, 0.f};
      z = __builtin_amdgcn_mfma_f32_16x16x32_bf16(Kf0, Qf[0], z, 0, 0, 0);
      S[jt] = __builtin_amdgcn_mfma_f32_16x16x32_bf16(Kf1, Qf[1], z, 0, 0, 0);
    }
    __builtin_amdgcn_s_setprio(0);

    if (kt == ntiles - 1) {
      const int jb = kt * 128 + 4 * g;
      #pragma unroll
      for (int jt = 0; jt < 8; ++jt)
        #pragma unroll
        for (int r = 0; r < 4; ++r)
          if (jb + 16 * jt + r > qrow) S[jt][r] = -1e30f;
    }

    float tm = -1e30f;
    #pragma unroll
    for (int jt = 0; jt < 8; ++jt)
      #pragma unroll
      for (int r = 0; r < 4; ++r) tm = fmaxf(tm, S[jt][r]);
    tm = fmaxf(tm, __shfl_xor(tm, 16));
    tm = fmaxf(tm, __shfl_xor(tm, 32));
    const float mn = fmaxf(m_run, tm);
    const float resc = __expf(m_run - mn);
    m_run = mn;
    float ts = 0.f;
    #pragma unroll
    for (int jt = 0; jt < 8; ++jt)
      #pragma unroll
      for (int r = 0; r < 4; ++r) {
        const float p = __expf(S[jt][r] - mn);
        S[jt][r] = p;
        ts += p;
      }
    ts += __shfl_xor(ts, 16);
    ts += __shfl_xor(ts, 32);
    l_run = l_run * resc + ts;
    #pragma unroll
    for (int dc = 0; dc < 4; ++dc) Oacc[dc] *= resc;

    uint4v PA[4];
    const bool hihalf = (g >= 2);
    const bool oddg = (g & 1);
    #pragma unroll
    for (int c = 0; c < 4; ++c) {
      const unsigned e_lo = pkbf(S[2 * c][0], S[2 * c][1]);
      const unsigned e_hi = pkbf(S[2 * c][2], S[2 * c][3]);
      const unsigned o_lo = pkbf(S[2 * c + 1][0], S[2 * c + 1][1]);
      const unsigned o_hi = pkbf(S[2 * c + 1][2], S[2 * c + 1][3]);
      const unsigned xe_lo = (unsigned)__shfl_xor((int)e_lo, 32);
      const unsigned xe_hi = (unsigned)__shfl_xor((int)e_hi, 32);
      const unsigned xo_lo = (unsigned)__shfl_xor((int)o_lo, 32);
      const unsigned xo_hi = (unsigned)__shfl_xor((int)o_hi, 32);
      const unsigned ap_lo = hihalf ? xo_lo : e_lo;
      const unsigned ap_hi = hihalf ? xo_hi : e_hi;
      const unsigned bp_lo = hihalf ? o_lo : xe_lo;
      const unsigned bp_hi = hihalf ? o_hi : xe_hi;
      const unsigned sa_lo = (unsigned)__shfl_xor((int)ap_lo, 16);
      const unsigned sa_hi = (unsigned)__shfl_xor((int)ap_hi, 16);
      const unsigned sb_lo = (unsigned)__shfl_xor((int)bp_lo, 16);
      const unsigned sb_hi = (unsigned)__shfl_xor((int)bp_hi, 16);
      PA[c][0] = oddg ? sb_lo : ap_lo;
      PA[c][1] = oddg ? sb_hi : ap_hi;
      PA[c][2] = oddg ? bp_lo : sa_lo;
      PA[c][3] = oddg ? bp_hi : sa_hi;
    }

    __builtin_amdgcn_s_setprio(1);
    #pragma unroll
    for (int dc = 0; dc < 4; ++dc) {
      #pragma unroll
      for (int c = 0; c < 4; ++c) {
        short8 Vf = *(const short8*)&Vlds[16 * dc + x][32 * c + 8 * g];
        Oacc[dc] = __builtin_amdgcn_mfma_f32_16x16x32_bf16(
            Vf, *(const short8*)&PA[c], Oacc[dc], 0, 0, 0);
      }
    }
    __builtin_amdgcn_s_setprio(0);
  }

  // epilogue: O[q=qrow][d_abs = h*64 + 16dc + 4g + r].
  // AOh: row-major [B,S,D]. AOl: FRAG layout for gemm_out3:
  //   mt = (b*2048+qrow)/16 = b*128 + 4*qt + w; kc = 2h + (dc>>1);
  //   slot = (2*(dc&1) + (g>>1))*16 + x; elems 4*(g&1) + r (contiguous).
  const float inv = 1.f / l_run;
  const size_t baseh = ((size_t)(b * SLEN + qrow)) * DDIM + h * HD + 4 * g;
  const int mt = b * 128 + 4 * qt + w;
  #pragma unroll
  for (int dc = 0; dc < 4; ++dc) {
    short4v hi4, lo4;
    #pragma unroll
    for (int r = 0; r < 4; ++r) {
      const float v = Oacc[dc][r] * inv;
      const short hh = f2bf(v);
      hi4[r] = hh;
      lo4[r] = f2bf(v - bf2f(hh));
    }
    *(short4v*)(AOh + baseh + 16 * dc) = hi4;
    const size_t lof =
        frag_off(mt, 2 * h + (dc >> 1),
                 ((2 * (dc & 1) + (g >> 1)) * 16 + x) * 8) +
        4 * (g & 1);
    *(short4v*)(AOl + lof) = lo4;
  }
}

// ---------------------------------------------------------------------------
extern "C" void kernel_launch(void* const* d_in, const int* in_sizes, int n_in,
                              void* d_out, int out_size, void* d_ws, size_t ws_size,
                              hipStream_t stream) {
  const float* x  = (const float*)d_in[0];
  const float* Wq = (const float*)d_in[1];
  const float* bq = (const float*)d_in[2];
  const float* Wk = (const float*)d_in[3];
  const float* bk = (const float*)d_in[4];
  const float* Wv = (const float*)d_in[5];
  const float* bv = (const float*)d_in[6];
  const float* Wo = (const float*)d_in[7];
  const float* bo = (const float*)d_in[8];
  float* out = (float*)d_out;

  short* S = (short*)d_ws;
  short* AOh = S;                       // aliases x_hi (free after gemm_qkv3)
  short* AOl = S + P_ELEM;              // aliases x_lo (frag layout)
  const short* Wo_h = S + 2 * P_ELEM + 6 * PW_ELEM;
  const short* Wo_l = Wo_h + PW_ELEM;
  short* Qb = S + 2 * P_ELEM + 8 * PW_ELEM;
  short* Kb = Qb + P_ELEM;
  short* Vb = Kb + P_ELEM;

  dim3 blk(256);
  cvt_split<<<dim3(768, 1, 5), blk, 0, stream>>>(x, Wq, Wk, Wv, Wo, S);
  gemm_qkv3<<<dim3(DDIM / 96, MROWS / 128, 3), blk, 0, stream>>>(
      S, bq, bk, bv, Qb, Kb, Vb);
  flash_fwd_mfma<<<dim3(BD * HNUM, SLEN / 64), blk, 0, stream>>>(
      Qb, Kb, Vb, AOh, AOl);
  gemm_out3<<<dim3(DDIM / 64, MROWS / 64), blk, 0, stream>>>(
      AOh, AOl, Wo_h, Wo_l, bo, out);
}